// Round 1
// 5923.755 us; speedup vs baseline: 1.4082x; 1.4082x over previous
//
#include <hip/hip_runtime.h>
#include <stdint.h>

// Problem constants
#define T_SEQ 256
#define BATCH 32
#define EDIM  512
#define G4    2048      // 4*E
#define VOCAB 16000
#define ROWS  8192      // B*T

typedef unsigned short u16;
typedef short bf16x8 __attribute__((ext_vector_type(8)));   // 8 bf16 = 4 VGPRs (MFMA A/B frag)
typedef float f32x4  __attribute__((ext_vector_type(4)));   // MFMA C/D frag

__device__ __forceinline__ u16 f2bf(float x) {              // RNE f32 -> bf16
  union { float f; uint32_t u; } v; v.f = x;
  return (u16)((v.u + 0x7fffu + ((v.u >> 16) & 1u)) >> 16);
}
__device__ __forceinline__ float bf2f(u16 x) {
  union { uint32_t u; float f; } v; v.u = ((uint32_t)x) << 16;
  return v.f;
}
__device__ __forceinline__ float sig_(float x) { return 1.0f / (1.0f + __expf(-x)); }
__device__ __forceinline__ float tanh_(float x) { return 2.0f / (1.0f + __expf(-2.0f * x)) - 1.0f; }

// ---------------------------------------------------------------- zero init
__global__ void zero_kernel(uint4* __restrict__ p, int n16) {
  int i = blockIdx.x * 256 + threadIdx.x;
  if (i < n16) p[i] = make_uint4(0u, 0u, 0u, 0u);
}

// ---------------------------------------------------------------- embedding gather (f32 -> bf16)
__global__ void gather_kernel(const int* __restrict__ inputs, const float* __restrict__ Emat,
                              u16* __restrict__ out) {
  const int r = blockIdx.x;                 // r = b*T + t (natural [B,T] flat order)
  const int idx = inputs[r];
  const float* src = Emat + (size_t)idx * EDIM;
  u16* dst = out + (size_t)r * EDIM;
  for (int e = threadIdx.x; e < EDIM; e += 256) dst[e] = f2bf(src[e]);
}

// ---------------------------------------------------------------- transpose + cast: src[K][N] f32 -> dst rows n: dst[n*stride + off + k] bf16
__global__ void transpose_cast_kernel(const float* __restrict__ src, u16* __restrict__ dst,
                                      int srcCols, int dstStride, int dstColOff) {
  __shared__ float tile[32][33];
  const int n0 = blockIdx.x * 32, k0 = blockIdx.y * 32;
  const int tx = threadIdx.x & 31, ty = threadIdx.x >> 5;   // 32 x 8
  #pragma unroll
  for (int p = 0; p < 32; p += 8)
    tile[ty + p][tx] = src[(size_t)(k0 + ty + p) * srcCols + n0 + tx];
  __syncthreads();
  #pragma unroll
  for (int p = 0; p < 32; p += 8)
    dst[(size_t)(n0 + ty + p) * dstStride + dstColOff + k0 + tx] = f2bf(tile[tx][ty + p]);
}

// ---------------------------------------------------------------- bf16 MFMA GEMM: C[M][N] = A[M][K] * BT[N][K]^T (+bias)
template<int OUT_BF16, int HAS_BIAS>
__launch_bounds__(256)
__global__ void gemm_bt_kernel(const u16* __restrict__ A, const u16* __restrict__ BT,
                               void* __restrict__ Cv, const float* __restrict__ bias,
                               int M, int N, int K) {
  __shared__ u16 sA[128 * 40];
  __shared__ u16 sB[128 * 40];
  const int tid = threadIdx.x;
  const int lane = tid & 63, wave = tid >> 6;
  const int wm = wave & 1, wn = wave >> 1;
  const int mr = lane & 15, kq = lane >> 4;
  const int row0 = blockIdx.y * 128, col0 = blockIdx.x * 128;
  const int srow = tid >> 2, scol = (tid & 3) * 8;
  f32x4 acc[4][4];
  #pragma unroll
  for (int i = 0; i < 4; ++i)
    #pragma unroll
    for (int j = 0; j < 4; ++j) acc[i][j] = (f32x4){0.f, 0.f, 0.f, 0.f};

  for (int k0 = 0; k0 < K; k0 += 32) {
    *(uint4*)&sA[srow * 40 + scol]        = *(const uint4*)&A[(size_t)(row0 + srow) * K + k0 + scol];
    *(uint4*)&sA[(srow + 64) * 40 + scol] = *(const uint4*)&A[(size_t)(row0 + srow + 64) * K + k0 + scol];
    *(uint4*)&sB[srow * 40 + scol]        = *(const uint4*)&BT[(size_t)(col0 + srow) * K + k0 + scol];
    *(uint4*)&sB[(srow + 64) * 40 + scol] = *(const uint4*)&BT[(size_t)(col0 + srow + 64) * K + k0 + scol];
    __syncthreads();
    bf16x8 af[4], bfr[4];
    #pragma unroll
    for (int i = 0; i < 4; ++i) af[i] = *(const bf16x8*)&sA[(wm * 64 + i * 16 + mr) * 40 + kq * 8];
    #pragma unroll
    for (int j = 0; j < 4; ++j) bfr[j] = *(const bf16x8*)&sB[(wn * 64 + j * 16 + mr) * 40 + kq * 8];
    #pragma unroll
    for (int i = 0; i < 4; ++i)
      #pragma unroll
      for (int j = 0; j < 4; ++j)
        acc[i][j] = __builtin_amdgcn_mfma_f32_16x16x32_bf16(af[i], bfr[j], acc[i][j], 0, 0, 0);
    __syncthreads();
  }
  #pragma unroll
  for (int j = 0; j < 4; ++j) {
    const int col = col0 + wn * 64 + j * 16 + mr;
    const float bv = HAS_BIAS ? bias[col] : 0.0f;
    #pragma unroll
    for (int i = 0; i < 4; ++i) {
      const int rbase = row0 + wm * 64 + i * 16 + kq * 4;
      #pragma unroll
      for (int r = 0; r < 4; ++r) {
        const float v = acc[i][j][r] + bv;
        if (OUT_BF16) ((u16*)Cv)[(size_t)(rbase + r) * N + col] = f2bf(v);
        else          ((float*)Cv)[(size_t)(rbase + r) * N + col] = v;
      }
    }
  }
}

// ---------------------------------------------------------------- persistent pipelined LSTM
// Blocks 0..31: layer 0 (e-slice of 16, 64 gate cols, wave w = gate w).
// Blocks 32..63: layer 1, one step behind, consuming h0(t) and h1(t-1).
// Weights live in REGISTERS (B-fragments) for the whole kernel.
// h0 ring: 4 slots; h1 ring: 2 slots. Cumulative arrival counters c0/c1 (32 blocks each):
//   L0@t: wait c0 >= 32t (peers' h0(t-1)) and c1 >= 32(t-3) (WAR on h0 ring slot t%4).
//   L1@t: wait c0 >= 32(t+1) (h0(t) ready; L0 runs ahead so ~free), c1 >= 32t (peers' h1(t-1)).
// Cell state c stays in registers (thread<->(b,e) map is static across t).
#define SGS 68

__device__ __forceinline__ void spin_ge(unsigned* c, unsigned target) {
  while (__hip_atomic_load(c, __ATOMIC_ACQUIRE, __HIP_MEMORY_SCOPE_AGENT) < target)
    __builtin_amdgcn_s_sleep(1);
}

#define LOAD_AF(SRC)                                                              \
  {                                                                               \
    _Pragma("unroll")                                                             \
    for (int i = 0; i < 2; ++i) {                                                 \
      const u16* ar_ = (SRC) + (i * 16 + mr) * EDIM + kq * 8;                     \
      _Pragma("unroll")                                                           \
      for (int ks = 0; ks < 16; ++ks) af[i][ks] = *(const bf16x8*)&ar_[ks * 32];  \
    }                                                                             \
  }

#define MFMA16(WOFF)                                                                             \
  {                                                                                              \
    _Pragma("unroll")                                                                            \
    for (int ks = 0; ks < 16; ++ks) {                                                            \
      a0 = __builtin_amdgcn_mfma_f32_16x16x32_bf16(af[0][ks], wr[(WOFF) + ks], a0, 0, 0, 0);     \
      a1 = __builtin_amdgcn_mfma_f32_16x16x32_bf16(af[1][ks], wr[(WOFF) + ks], a1, 0, 0, 0);     \
    }                                                                                            \
  }

#define SG_WRITE()                                                                \
  {                                                                               \
    _Pragma("unroll")                                                             \
    for (int r = 0; r < 4; ++r) {                                                 \
      sG[(kq * 4 + r) * SGS + w * 16 + mr]      = a0[r];                          \
      sG[(16 + kq * 4 + r) * SGS + w * 16 + mr] = a1[r];                          \
    }                                                                             \
  }

__launch_bounds__(256, 1)
__global__ void lstm_kernel(const u16* __restrict__ Xpre0, const u16* __restrict__ Wh0T,
                            const u16* __restrict__ W1T,
                            const float* __restrict__ b0, const float* __restrict__ b1,
                            u16* __restrict__ Hbuf0, u16* __restrict__ H1buf,
                            u16* __restrict__ H1all, unsigned* __restrict__ ctr) {
  __shared__ float sG[32 * SGS];                 // gate-transpose buffer (8.7 KB)
  const int tid = threadIdx.x;
  const int lane = tid & 63, w = tid >> 6;       // wave w = gate index
  const int mr = lane & 15, kq = lane >> 4;      // MFMA fragment coords
  const int b = tid >> 3, eu = (tid & 7) * 2;    // gate-math map: (batch, 2 e-elems)
  unsigned* c0 = ctr;
  unsigned* c1 = ctr + 64;                       // 256B apart
  const int bid = blockIdx.x;

  if (bid < 32) {
    // ================= layer 0 =================
    const int e0 = bid * 16;
    bf16x8 wr[16];                               // Wh0 B-frags, resident all 256 steps
    {
      const u16* Wrow = Wh0T + (size_t)(w * EDIM + e0 + mr) * EDIM;
      #pragma unroll
      for (int ks = 0; ks < 16; ++ks) wr[ks] = *(const bf16x8*)&Wrow[ks * 32 + kq * 8];
    }
    float bs[4][2];
    #pragma unroll
    for (int g = 0; g < 4; ++g) {
      bs[g][0] = b0[g * EDIM + e0 + eu];
      bs[g][1] = b0[g * EDIM + e0 + eu + 1];
    }
    float cst0 = 0.f, cst1 = 0.f;                // cell state in registers
    const u16* xrow = Xpre0 + (size_t)b * T_SEQ * G4 + e0 + eu;

    for (int t = 0; t < T_SEQ; ++t) {
      uint32_t xp[4];                            // prefetch x-part before the wait
      #pragma unroll
      for (int g = 0; g < 4; ++g) xp[g] = *(const uint32_t*)&xrow[(size_t)t * G4 + g * EDIM];
      if (tid == 0) {
        spin_ge(c0, 32u * (unsigned)t);                        // peers' h0(t-1)
        if (t >= 4) spin_ge(c1, 32u * (unsigned)(t - 3));      // WAR: L1 done with h0(t-4)
      }
      __syncthreads();
      __threadfence();
      const u16* hsrc = Hbuf0 + ((t + 3) & 3) * (BATCH * EDIM);
      bf16x8 af[2][16];
      LOAD_AF(hsrc);
      f32x4 a0 = (f32x4){0.f, 0.f, 0.f, 0.f}, a1 = (f32x4){0.f, 0.f, 0.f, 0.f};
      MFMA16(0);
      SG_WRITE();
      __syncthreads();
      float hv[2];
      #pragma unroll
      for (int u = 0; u < 2; ++u) {
        const float gi = sG[b * SGS + 0 * 16 + eu + u] + bs[0][u] + bf2f((u16)(xp[0] >> (16 * u)));
        const float gj = sG[b * SGS + 1 * 16 + eu + u] + bs[1][u] + bf2f((u16)(xp[1] >> (16 * u)));
        const float gf = sG[b * SGS + 2 * 16 + eu + u] + bs[2][u] + bf2f((u16)(xp[2] >> (16 * u)));
        const float go = sG[b * SGS + 3 * 16 + eu + u] + bs[3][u] + bf2f((u16)(xp[3] >> (16 * u)));
        float& cs = u ? cst1 : cst0;
        const float cn = sig_(gf + 1.0f) * cs + sig_(gi) * tanh_(gj);
        cs = cn;
        hv[u] = sig_(go) * tanh_(cn);
      }
      const uint32_t pk = (uint32_t)f2bf(hv[0]) | ((uint32_t)f2bf(hv[1]) << 16);
      *(uint32_t*)&Hbuf0[(t & 3) * (BATCH * EDIM) + b * EDIM + e0 + eu] = pk;
      __syncthreads();                           // all h-stores drained (vmcnt0 before barrier)
      if (tid == 0) {
        __threadfence();
        __hip_atomic_fetch_add(c0, 1u, __ATOMIC_RELEASE, __HIP_MEMORY_SCOPE_AGENT);
      }
    }
  } else {
    // ================= layer 1 =================
    const int e0 = (bid - 32) * 16;
    bf16x8 wr[32];                               // [Wx1;Wh1] B-frags, resident
    {
      const u16* Wrow = W1T + (size_t)(w * EDIM + e0 + mr) * (2 * EDIM);
      #pragma unroll
      for (int ks = 0; ks < 32; ++ks) wr[ks] = *(const bf16x8*)&Wrow[ks * 32 + kq * 8];
    }
    float bs[4][2];
    #pragma unroll
    for (int g = 0; g < 4; ++g) {
      bs[g][0] = b1[g * EDIM + e0 + eu];
      bs[g][1] = b1[g * EDIM + e0 + eu + 1];
    }
    float cst0 = 0.f, cst1 = 0.f;

    for (int t = 0; t < T_SEQ; ++t) {
      if (tid == 0) spin_ge(c0, 32u * (unsigned)(t + 1));      // h0(t) ready (L0 runs ahead)
      __syncthreads();
      __threadfence();
      bf16x8 af[2][16];
      const u16* h0src = Hbuf0 + (t & 3) * (BATCH * EDIM);
      LOAD_AF(h0src);
      f32x4 a0 = (f32x4){0.f, 0.f, 0.f, 0.f}, a1 = (f32x4){0.f, 0.f, 0.f, 0.f};
      MFMA16(0);                                 // x-part: h0(t) @ Wx1
      if (tid == 0) spin_ge(c1, 32u * (unsigned)t);            // peers' h1(t-1)
      __syncthreads();
      __threadfence();
      const u16* h1src = H1buf + ((t + 1) & 1) * (BATCH * EDIM);
      LOAD_AF(h1src);
      MFMA16(16);                                // h-part: h1(t-1) @ Wh1
      SG_WRITE();
      __syncthreads();
      float hv[2];
      #pragma unroll
      for (int u = 0; u < 2; ++u) {
        const float gi = sG[b * SGS + 0 * 16 + eu + u] + bs[0][u];
        const float gj = sG[b * SGS + 1 * 16 + eu + u] + bs[1][u];
        const float gf = sG[b * SGS + 2 * 16 + eu + u] + bs[2][u];
        const float go = sG[b * SGS + 3 * 16 + eu + u] + bs[3][u];
        float& cs = u ? cst1 : cst0;
        const float cn = sig_(gf + 1.0f) * cs + sig_(gi) * tanh_(gj);
        cs = cn;
        hv[u] = sig_(go) * tanh_(cn);
      }
      const uint32_t pk = (uint32_t)f2bf(hv[0]) | ((uint32_t)f2bf(hv[1]) << 16);
      *(uint32_t*)&H1buf[(t & 1) * (BATCH * EDIM) + b * EDIM + e0 + eu] = pk;
      *(uint32_t*)&H1all[((size_t)b * T_SEQ + t) * EDIM + e0 + eu] = pk;  // GEMM-A layout
      __syncthreads();
      if (tid == 0) {
        __threadfence();
        __hip_atomic_fetch_add(c1, 1u, __ATOMIC_RELEASE, __HIP_MEMORY_SCOPE_AGENT);
      }
    }
  }
}

// ---------------------------------------------------------------- per-row log-softmax NLL
__global__ void softmax_nll_kernel(const float* __restrict__ logits, const int* __restrict__ labels,
                                   float* __restrict__ nll) {
  __shared__ float red[256];
  const int r = blockIdx.x, tid = threadIdx.x;
  const float* row = logits + (size_t)r * VOCAB;
  float m = -1e30f;
  for (int i = tid; i < VOCAB; i += 256) m = fmaxf(m, row[i]);
  red[tid] = m; __syncthreads();
  for (int s = 128; s > 0; s >>= 1) { if (tid < s) red[tid] = fmaxf(red[tid], red[tid + s]); __syncthreads(); }
  m = red[0]; __syncthreads();
  float sum = 0.f;
  for (int i = tid; i < VOCAB; i += 256) sum += __expf(row[i] - m);
  red[tid] = sum; __syncthreads();
  for (int s = 128; s > 0; s >>= 1) { if (tid < s) red[tid] += red[tid + s]; __syncthreads(); }
  if (tid == 0) nll[r] = (m + __logf(red[0])) - row[labels[r]];
}

__global__ void ppl_kernel(const float* __restrict__ nll, float* __restrict__ out) {
  __shared__ float red[256];
  const int tid = threadIdx.x;
  float s = 0.f;
  for (int i = tid; i < ROWS; i += 256) s += nll[i];
  red[tid] = s; __syncthreads();
  for (int st = 128; st > 0; st >>= 1) { if (tid < st) red[tid] += red[tid + st]; __syncthreads(); }
  if (tid == 0) out[(size_t)ROWS * VOCAB] = __expf(red[0] / (float)ROWS);
}

// ---------------------------------------------------------------- host
extern "C" void kernel_launch(void* const* d_in, const int* in_sizes, int n_in,
                              void* d_out, int out_size, void* d_ws, size_t ws_size,
                              hipStream_t stream) {
  const int*   inputs = (const int*)d_in[0];
  const int*   labels = (const int*)d_in[1];
  const float* Emat   = (const float*)d_in[2];
  const float* Wx0    = (const float*)d_in[3];
  const float* Wh0    = (const float*)d_in[4];
  const float* b0     = (const float*)d_in[5];
  const float* Wx1    = (const float*)d_in[6];
  const float* Wh1    = (const float*)d_in[7];
  const float* b1     = (const float*)d_in[8];
  const float* Wd     = (const float*)d_in[9];
  const float* bd     = (const float*)d_in[10];

  char* ws = (char*)d_ws;
  size_t off = 0;
  auto alloc = [&](size_t bytes) { size_t o = off; off += (bytes + 255) & ~(size_t)255; return o; };
  u16* embeds = (u16*)(ws + alloc((size_t)ROWS * EDIM * 2));          // bf16 A for bulk GEMM
  u16* Wx0T   = (u16*)(ws + alloc((size_t)G4 * EDIM * 2));
  u16* Wh0T   = (u16*)(ws + alloc((size_t)G4 * EDIM * 2));
  u16* W1T    = (u16*)(ws + alloc((size_t)G4 * 2 * EDIM * 2));        // [Wx1;Wh1] cols, rows of 1024
  u16* WdT    = (u16*)(ws + alloc((size_t)VOCAB * EDIM * 2));
  u16* Xpre0  = (u16*)(ws + alloc((size_t)ROWS * G4 * 2));
  u16* H1all  = (u16*)(ws + alloc((size_t)ROWS * EDIM * 2));
  char* zbase = ws + off;                                             // ---- zeroed region ----
  u16*   Hbuf0 = (u16*)(ws + alloc(4 * BATCH * EDIM * 2));            // h0 ring, 4 slots
  u16*   H1buf = (u16*)(ws + alloc(2 * BATCH * EDIM * 2));            // h1 ring, 2 slots
  unsigned* ctr = (unsigned*)(ws + alloc(512));                       // c0 @ +0, c1 @ +256
  float* nll   = (float*)(ws + alloc(ROWS * 4));
  const size_t zbytes = (size_t)((ws + off) - zbase);

  const int n16 = (int)(zbytes / 16);
  zero_kernel<<<(n16 + 255) / 256, 256, 0, stream>>>((uint4*)zbase, n16);
  gather_kernel<<<ROWS, 256, 0, stream>>>(inputs, Emat, embeds);
  transpose_cast_kernel<<<dim3(G4 / 32, EDIM / 32), 256, 0, stream>>>(Wx0, Wx0T, G4, EDIM, 0);
  transpose_cast_kernel<<<dim3(G4 / 32, EDIM / 32), 256, 0, stream>>>(Wh0, Wh0T, G4, EDIM, 0);
  transpose_cast_kernel<<<dim3(G4 / 32, EDIM / 32), 256, 0, stream>>>(Wx1, W1T, G4, 2 * EDIM, 0);
  transpose_cast_kernel<<<dim3(G4 / 32, EDIM / 32), 256, 0, stream>>>(Wh1, W1T, G4, 2 * EDIM, EDIM);
  transpose_cast_kernel<<<dim3(VOCAB / 32, EDIM / 32), 256, 0, stream>>>(Wd, WdT, VOCAB, EDIM, 0);
  // Xpre0 = embeds @ Wx0 (bias added in lstm kernel)
  gemm_bt_kernel<1, 0><<<dim3(G4 / 128, ROWS / 128), 256, 0, stream>>>(embeds, Wx0T, Xpre0, nullptr, ROWS, G4, EDIM);
  lstm_kernel<<<64, 256, 0, stream>>>(Xpre0, Wh0T, W1T, b0, b1, Hbuf0, H1buf, H1all, ctr);
  // logits = H1all @ Wd + bd  -> d_out
  gemm_bt_kernel<0, 1><<<dim3(VOCAB / 128, ROWS / 128), 256, 0, stream>>>(H1all, WdT, d_out, bd, ROWS, VOCAB, EDIM);
  softmax_nll_kernel<<<ROWS, 256, 0, stream>>>((const float*)d_out, labels, nll);
  ppl_kernel<<<1, 256, 0, stream>>>(nll, (float*)d_out);
}